// Round 2
// baseline (52184.418 us; speedup 1.0000x reference)
//
#include <hip/hip_runtime.h>
#include <cstddef>

#define NOBJ 50000
#define NTRI 250000

__device__ __forceinline__ float leaky(float x) { return x > 0.0f ? x : 0.2f * x; }

// ---------------------------------------------------------------------------
// Embedding: obj = leaky([obj_vecs | boxes] @ W_emb + b_emb)   (O x 68) @ (68 x 64)
// Writes obj at row-stride 64.
// ---------------------------------------------------------------------------
__global__ __launch_bounds__(256) void embed_kernel(
    const float* __restrict__ obj_vecs, const float* __restrict__ boxes,
    const float* __restrict__ W, const float* __restrict__ b,
    float* __restrict__ out)
{
    __shared__ float Ws[68 * 64];
    const int tid = threadIdx.x;
    for (int i = tid; i < 68 * 64; i += 256) Ws[i] = W[i];
    __syncthreads();
    const int row = blockIdx.x * 4 + (tid >> 6);
    const int col = tid & 63;
    if (row >= NOBJ) return;
    float acc = b[col];
    const float* __restrict__ a = obj_vecs + (size_t)row * 64;
#pragma unroll 16
    for (int k = 0; k < 64; ++k) acc = fmaf(a[k], Ws[k * 64 + col], acc);
    const float* __restrict__ bx = boxes + (size_t)row * 4;
#pragma unroll
    for (int k = 0; k < 4; ++k) acc = fmaf(bx[k], Ws[(64 + k) * 64 + col], acc);
    out[(size_t)row * 64 + col] = leaky(acc);
}

// ---------------------------------------------------------------------------
// Degree counts (same for every layer), then invert: c -> 1/max(c,1)
// ---------------------------------------------------------------------------
__global__ __launch_bounds__(256) void count_kernel(
    const int* __restrict__ s, const int* __restrict__ o, float* __restrict__ cnt)
{
    const int t = blockIdx.x * 256 + threadIdx.x;
    if (t < NTRI) {
        atomicAdd(&cnt[s[t]], 1.0f);
        atomicAdd(&cnt[o[t]], 1.0f);
    }
}

__global__ __launch_bounds__(256) void invcnt_kernel(float* __restrict__ cnt)
{
    const int i = blockIdx.x * 256 + threadIdx.x;
    if (i < NOBJ) cnt[i] = 1.0f / fmaxf(cnt[i], 1.0f);
}

// ---------------------------------------------------------------------------
// Tiled f32 GEMM, 128x128 tile, KB=32, 256 threads, 8x8 micro-tile.
// Rows are CHUNK-LOCAL (M = chunk rows); pointers are pre-offset by the host.
// AMODE:
//   AM_PLAIN  : A0 row-major M x K
//   AM_GATHER : A row m = [ obj[sidx[m]] | pred[m] | obj[oidx[m]] ], each DIN wide
//               (A0 = obj base, GLOBAL indices; A1 = pred chunk base)
//   AM_SCALED : A0 row-major M x K, row m scaled by A1[m] (1/count)
// EPMODE:
//   EP_STORE  : C0[m, n] = leaky(acc + bias[n])          (C0 is M x NTOT)
//   EP_SPLIT  : N-chunks map to [s | p | o]:
//                 s: atomicAdd into C0[sidx[m]*H + col]           (global pooled)
//                 p: store to C1[m*DOUT + col-H]                  (chunk-local pred)
//                 o: atomicAdd into C0[oidx[m]*H + col-H-DOUT]
// ---------------------------------------------------------------------------
enum { AM_PLAIN = 0, AM_GATHER = 1, AM_SCALED = 2 };
enum { EP_STORE = 0, EP_SPLIT = 1 };

template <int AMODE, int EPMODE, int DIN, int K, int H, int DOUT, int NTOT>
__global__ __launch_bounds__(256, 2) void sgemm_kernel(
    const float* __restrict__ A0, const float* __restrict__ A1,
    const int* __restrict__ sidx, const int* __restrict__ oidx,
    const float* __restrict__ W, const float* __restrict__ bias,
    float* __restrict__ C0, float* __restrict__ C1, int M)
{
    constexpr int BM = 128, BN = 128, KB = 32;
    __shared__ float As[KB][BM + 4];   // A transposed: As[k][m]; row = 132 floats = 528 B (16B-aligned)
    __shared__ float Bs[KB][BN + 4];

    const int tid = threadIdx.x;
    const int tx = tid & 15;
    const int ty = tid >> 4;
    const int m0 = blockIdx.x * BM;
    const int n0 = blockIdx.y * BN;

    float acc[8][8];
#pragma unroll
    for (int i = 0; i < 8; ++i)
#pragma unroll
        for (int j = 0; j < 8; ++j) acc[i][j] = 0.0f;

    // A staging: each thread loads 16 consecutive K-floats of one row (4x float4)
    const int arow = tid >> 1;
    const int akb  = (tid & 1) * 16;
    int am = m0 + arow;
    if (am > M - 1) am = M - 1;          // clamp tail (stores are guarded)

    // B staging: each thread loads 4x float4 along N
    const int bkr = tid >> 5;
    const int bn  = (tid & 31) * 4;

    float ascale = 1.0f;
    if (AMODE == AM_SCALED) ascale = A1[am];
    int asrow = 0, aorow = 0;
    if (AMODE == AM_GATHER) { asrow = sidx[am]; aorow = oidx[am]; }

#pragma unroll 1
    for (int k0 = 0; k0 < K; k0 += KB) {
        __syncthreads();
        // ---- stage A (transposed into LDS) ----
        {
            const float* src;
            if (AMODE == AM_GATHER) {
                // KB=32 divides DIN => each K-chunk comes from exactly one source
                if (k0 < DIN)            src = A0 + (size_t)asrow * DIN + k0;
                else if (k0 < 2 * DIN)   src = A1 + (size_t)am * DIN + (k0 - DIN);
                else                     src = A0 + (size_t)aorow * DIN + (k0 - 2 * DIN);
            } else {
                src = A0 + (size_t)am * K + k0;
            }
#pragma unroll
            for (int q = 0; q < 4; ++q) {
                float4 v = *reinterpret_cast<const float4*>(src + akb + q * 4);
                if (AMODE == AM_SCALED) { v.x *= ascale; v.y *= ascale; v.z *= ascale; v.w *= ascale; }
                const int lk = akb + q * 4;
                As[lk + 0][arow] = v.x;
                As[lk + 1][arow] = v.y;
                As[lk + 2][arow] = v.z;
                As[lk + 3][arow] = v.w;
            }
        }
        // ---- stage B ----
#pragma unroll
        for (int q = 0; q < 4; ++q) {
            const int kr = bkr + q * 8;
            const float4 v = *reinterpret_cast<const float4*>(W + (size_t)(k0 + kr) * NTOT + n0 + bn);
            *reinterpret_cast<float4*>(&Bs[kr][bn]) = v;
        }
        __syncthreads();
        // ---- compute ----
#pragma unroll
        for (int kk = 0; kk < KB; ++kk) {
            float a[8], b[8];
            *reinterpret_cast<float4*>(&a[0]) = *reinterpret_cast<const float4*>(&As[kk][ty * 8]);
            *reinterpret_cast<float4*>(&a[4]) = *reinterpret_cast<const float4*>(&As[kk][ty * 8 + 4]);
            *reinterpret_cast<float4*>(&b[0]) = *reinterpret_cast<const float4*>(&Bs[kk][tx * 4]);
            *reinterpret_cast<float4*>(&b[4]) = *reinterpret_cast<const float4*>(&Bs[kk][64 + tx * 4]);
#pragma unroll
            for (int i = 0; i < 8; ++i)
#pragma unroll
                for (int j = 0; j < 8; ++j)
                    acc[i][j] = fmaf(a[i], b[j], acc[i][j]);
        }
    }

    // ---- epilogue ----
    float bv[8];
#pragma unroll
    for (int j = 0; j < 4; ++j) {
        bv[j]     = bias[n0 + tx * 4 + j];
        bv[4 + j] = bias[n0 + 64 + tx * 4 + j];
    }

#pragma unroll
    for (int i = 0; i < 8; ++i) {
        const int r = m0 + ty * 8 + i;
        if (r >= M) continue;
        if (EPMODE == EP_STORE) {
            float4 v0, v1;
            v0.x = leaky(acc[i][0] + bv[0]);
            v0.y = leaky(acc[i][1] + bv[1]);
            v0.z = leaky(acc[i][2] + bv[2]);
            v0.w = leaky(acc[i][3] + bv[3]);
            v1.x = leaky(acc[i][4] + bv[4]);
            v1.y = leaky(acc[i][5] + bv[5]);
            v1.z = leaky(acc[i][6] + bv[6]);
            v1.w = leaky(acc[i][7] + bv[7]);
            *reinterpret_cast<float4*>(&C0[(size_t)r * NTOT + n0 + tx * 4])      = v0;
            *reinterpret_cast<float4*>(&C0[(size_t)r * NTOT + n0 + 64 + tx * 4]) = v1;
        } else {
            constexpr int SCH = H / 128;        // number of s-chunks; p is exactly one chunk (DOUT==128)
            const int chunk = blockIdx.y;
            if (chunk < SCH) {
                float* dst = C0 + (size_t)sidx[r] * H + n0;
#pragma unroll
                for (int j = 0; j < 4; ++j) {
                    atomicAdd(dst + tx * 4 + j,      leaky(acc[i][j]     + bv[j]));
                    atomicAdd(dst + 64 + tx * 4 + j, leaky(acc[i][4 + j] + bv[4 + j]));
                }
            } else if (chunk == SCH) {
                float4 v0, v1;
                v0.x = leaky(acc[i][0] + bv[0]);
                v0.y = leaky(acc[i][1] + bv[1]);
                v0.z = leaky(acc[i][2] + bv[2]);
                v0.w = leaky(acc[i][3] + bv[3]);
                v1.x = leaky(acc[i][4] + bv[4]);
                v1.y = leaky(acc[i][5] + bv[5]);
                v1.z = leaky(acc[i][6] + bv[6]);
                v1.w = leaky(acc[i][7] + bv[7]);
                float* dst = C1 + (size_t)r * DOUT + (n0 - H);
                *reinterpret_cast<float4*>(dst + tx * 4)      = v0;
                *reinterpret_cast<float4*>(dst + 64 + tx * 4) = v1;
            } else {
                float* dst = C0 + (size_t)oidx[r] * H + (n0 - H - DOUT);
#pragma unroll
                for (int j = 0; j < 4; ++j) {
                    atomicAdd(dst + tx * 4 + j,      leaky(acc[i][j]     + bv[j]));
                    atomicAdd(dst + 64 + tx * 4 + j, leaky(acc[i][4 + j] + bv[4 + j]));
                }
            }
        }
    }
}

// ---------------------------------------------------------------------------
// Final: out = leaky(obj @ W_bb + b_bb)   (O x 128) @ (128 x 4)
// ---------------------------------------------------------------------------
__global__ __launch_bounds__(256) void final_kernel(
    const float* __restrict__ obj, const float* __restrict__ W,
    const float* __restrict__ b, float* __restrict__ out)
{
    __shared__ float Ws[128 * 4];
    const int tid = threadIdx.x;
    for (int i = tid; i < 512; i += 256) Ws[i] = W[i];
    __syncthreads();
    const int r = blockIdx.x * 256 + tid;
    if (r >= NOBJ) return;
    float a0 = b[0], a1 = b[1], a2 = b[2], a3 = b[3];
    const float* __restrict__ a = obj + (size_t)r * 128;
#pragma unroll 8
    for (int k = 0; k < 128; k += 4) {
        const float4 v = *reinterpret_cast<const float4*>(a + k);
        a0 = fmaf(v.x, Ws[(k + 0) * 4 + 0], a0);
        a1 = fmaf(v.x, Ws[(k + 0) * 4 + 1], a1);
        a2 = fmaf(v.x, Ws[(k + 0) * 4 + 2], a2);
        a3 = fmaf(v.x, Ws[(k + 0) * 4 + 3], a3);
        a0 = fmaf(v.y, Ws[(k + 1) * 4 + 0], a0);
        a1 = fmaf(v.y, Ws[(k + 1) * 4 + 1], a1);
        a2 = fmaf(v.y, Ws[(k + 1) * 4 + 2], a2);
        a3 = fmaf(v.y, Ws[(k + 1) * 4 + 3], a3);
        a0 = fmaf(v.z, Ws[(k + 2) * 4 + 0], a0);
        a1 = fmaf(v.z, Ws[(k + 2) * 4 + 1], a1);
        a2 = fmaf(v.z, Ws[(k + 2) * 4 + 2], a2);
        a3 = fmaf(v.z, Ws[(k + 2) * 4 + 3], a3);
        a0 = fmaf(v.w, Ws[(k + 3) * 4 + 0], a0);
        a1 = fmaf(v.w, Ws[(k + 3) * 4 + 1], a1);
        a2 = fmaf(v.w, Ws[(k + 3) * 4 + 2], a2);
        a3 = fmaf(v.w, Ws[(k + 3) * 4 + 3], a3);
    }
    float4 o;
    o.x = leaky(a0);
    o.y = leaky(a1);
    o.z = leaky(a2);
    o.w = leaky(a3);
    *reinterpret_cast<float4*>(out + (size_t)r * 4) = o;
}

// ---------------------------------------------------------------------------
// Host orchestration — chunked, ws_size-adaptive.
// Workspace (floats):
//   pred   : T*128          (in-place across layers; rewritten chunk-by-chunk)
//   pooled : O*512
//   obj    : O*128          (in-place across layers; layer0 uses stride 64)
//   counts : O
//   scr    : CH*512         (edge hid chunk / node hid chunk, time-shared)
// Fixed part = 64.05M floats (256.2 MB); CH adapts to ws_size (cap 50176 rows).
// ---------------------------------------------------------------------------
extern "C" void kernel_launch(void* const* d_in, const int* in_sizes, int n_in,
                              void* d_out, int out_size, void* d_ws, size_t ws_size,
                              hipStream_t stream)
{
    const float* obj_vecs   = (const float*)d_in[0];
    const float* pred_vecs  = (const float*)d_in[1];
    const float* pred_boxes = (const float*)d_in[2];
    const int*   s_idx      = (const int*)d_in[3];
    const int*   o_idx      = (const int*)d_in[4];
    const float* W_emb      = (const float*)d_in[5];
    const float* b_emb      = (const float*)d_in[6];
    const float* W_bb       = (const float*)d_in[39];
    const float* b_bb       = (const float*)d_in[40];
    auto LP = [&](int layer, int which) -> const float* {
        return (const float*)d_in[7 + layer * 8 + which];
    };

    // ---- adaptive chunk size ----
    const size_t FIXED = (size_t)NTRI * 128 + (size_t)NOBJ * 512 + (size_t)NOBJ * 128 + (size_t)NOBJ;
    size_t ws_floats = ws_size / sizeof(float);
    size_t avail = ws_floats > FIXED ? ws_floats - FIXED : 0;
    long long ch = (long long)(avail / 512);
    ch = (ch / 128) * 128;
    if (ch > 50176) ch = 50176;   // 5 edge chunks; node pipeline single-chunk
    if (ch < 128)   ch = 128;     // ws too small to be correct; best effort
    const int CH = (int)ch;

    float* pred   = (float*)d_ws;                          // T*128
    float* pooled = pred   + (size_t)NTRI * 128;           // O*512
    float* obj    = pooled + (size_t)NOBJ * 512;           // O*128
    float* counts = obj    + (size_t)NOBJ * 128;           // O
    float* scr    = counts + NOBJ;                         // CH*512

    const dim3 blk(256);

    hipMemsetAsync(counts, 0, NOBJ * sizeof(float), stream);
    embed_kernel<<<(NOBJ + 3) / 4, blk, 0, stream>>>(obj_vecs, pred_boxes, W_emb, b_emb, obj);
    count_kernel<<<(NTRI + 255) / 256, blk, 0, stream>>>(s_idx, o_idx, counts);
    invcnt_kernel<<<(NOBJ + 255) / 256, blk, 0, stream>>>(counts);

    // ---------------- layer 0: DIN=64, K1=192, H=512, DOUT=128 ----------------
    hipMemsetAsync(pooled, 0, (size_t)NOBJ * 512 * sizeof(float), stream);
    for (int r0 = 0; r0 < NTRI; r0 += CH) {
        const int CM = (NTRI - r0 < CH) ? (NTRI - r0) : CH;
        const int mt = (CM + 127) / 128;
        sgemm_kernel<AM_GATHER, EP_STORE, 64, 192, 512, 128, 512><<<dim3(mt, 4), blk, 0, stream>>>(
            obj, pred_vecs + (size_t)r0 * 64, s_idx + r0, o_idx + r0, LP(0, 0), LP(0, 1), scr, nullptr, CM);
        sgemm_kernel<AM_PLAIN, EP_SPLIT, 0, 512, 512, 128, 1152><<<dim3(mt, 9), blk, 0, stream>>>(
            scr, nullptr, s_idx + r0, o_idx + r0, LP(0, 2), LP(0, 3), pooled, pred + (size_t)r0 * 128, CM);
    }
    for (int r0 = 0; r0 < NOBJ; r0 += CH) {
        const int CM = (NOBJ - r0 < CH) ? (NOBJ - r0) : CH;
        const int mt = (CM + 127) / 128;
        sgemm_kernel<AM_SCALED, EP_STORE, 0, 512, 512, 128, 512><<<dim3(mt, 4), blk, 0, stream>>>(
            pooled + (size_t)r0 * 512, counts + r0, nullptr, nullptr, LP(0, 4), LP(0, 5), scr, nullptr, CM);
        sgemm_kernel<AM_PLAIN, EP_STORE, 0, 512, 512, 128, 128><<<dim3(mt, 1), blk, 0, stream>>>(
            scr, nullptr, nullptr, nullptr, LP(0, 6), LP(0, 7), obj + (size_t)r0 * 128, nullptr, CM);
    }

    // ---------------- layers 1,2: DIN=128, K1=384, H=512, DOUT=128 ----------------
    for (int L = 1; L <= 2; ++L) {
        hipMemsetAsync(pooled, 0, (size_t)NOBJ * 512 * sizeof(float), stream);
        for (int r0 = 0; r0 < NTRI; r0 += CH) {
            const int CM = (NTRI - r0 < CH) ? (NTRI - r0) : CH;
            const int mt = (CM + 127) / 128;
            sgemm_kernel<AM_GATHER, EP_STORE, 128, 384, 512, 128, 512><<<dim3(mt, 4), blk, 0, stream>>>(
                obj, pred + (size_t)r0 * 128, s_idx + r0, o_idx + r0, LP(L, 0), LP(L, 1), scr, nullptr, CM);
            sgemm_kernel<AM_PLAIN, EP_SPLIT, 0, 512, 512, 128, 1152><<<dim3(mt, 9), blk, 0, stream>>>(
                scr, nullptr, s_idx + r0, o_idx + r0, LP(L, 2), LP(L, 3), pooled, pred + (size_t)r0 * 128, CM);
        }
        for (int r0 = 0; r0 < NOBJ; r0 += CH) {
            const int CM = (NOBJ - r0 < CH) ? (NOBJ - r0) : CH;
            const int mt = (CM + 127) / 128;
            sgemm_kernel<AM_SCALED, EP_STORE, 0, 512, 512, 128, 512><<<dim3(mt, 4), blk, 0, stream>>>(
                pooled + (size_t)r0 * 512, counts + r0, nullptr, nullptr, LP(L, 4), LP(L, 5), scr, nullptr, CM);
            sgemm_kernel<AM_PLAIN, EP_STORE, 0, 512, 512, 128, 128><<<dim3(mt, 1), blk, 0, stream>>>(
                scr, nullptr, nullptr, nullptr, LP(L, 6), LP(L, 7), obj + (size_t)r0 * 128, nullptr, CM);
        }
    }

    // ---------------- layer 3: DIN=128, K1=384, H=128, DOUT=128 ----------------
    hipMemsetAsync(pooled, 0, (size_t)NOBJ * 128 * sizeof(float), stream);
    for (int r0 = 0; r0 < NTRI; r0 += CH) {
        const int CM = (NTRI - r0 < CH) ? (NTRI - r0) : CH;
        const int mt = (CM + 127) / 128;
        sgemm_kernel<AM_GATHER, EP_STORE, 128, 384, 128, 128, 128><<<dim3(mt, 1), blk, 0, stream>>>(
            obj, pred + (size_t)r0 * 128, s_idx + r0, o_idx + r0, LP(3, 0), LP(3, 1), scr, nullptr, CM);
        sgemm_kernel<AM_PLAIN, EP_SPLIT, 0, 128, 128, 128, 384><<<dim3(mt, 3), blk, 0, stream>>>(
            scr, nullptr, s_idx + r0, o_idx + r0, LP(3, 2), LP(3, 3), pooled, pred + (size_t)r0 * 128, CM);
    }
    for (int r0 = 0; r0 < NOBJ; r0 += CH) {
        const int CM = (NOBJ - r0 < CH) ? (NOBJ - r0) : CH;
        const int mt = (CM + 127) / 128;
        sgemm_kernel<AM_SCALED, EP_STORE, 0, 128, 128, 128, 128><<<dim3(mt, 1), blk, 0, stream>>>(
            pooled + (size_t)r0 * 128, counts + r0, nullptr, nullptr, LP(3, 4), LP(3, 5), scr, nullptr, CM);
        sgemm_kernel<AM_PLAIN, EP_STORE, 0, 128, 128, 128, 128><<<dim3(mt, 1), blk, 0, stream>>>(
            scr, nullptr, nullptr, nullptr, LP(3, 6), LP(3, 7), obj + (size_t)r0 * 128, nullptr, CM);
    }

    // ---------------- final projection ----------------
    final_kernel<<<(NOBJ + 255) / 256, blk, 0, stream>>>(obj, W_bb, b_bb, (float*)d_out);
}